// Round 11
// baseline (575.778 us; speedup 1.0000x reference)
//
#include <hip/hip_runtime.h>

#define C 64

typedef float f4 __attribute__((ext_vector_type(4)));

// ---------------------------------------------------------------------------
// R8 (proven, 434us) + minimal bimodal count-split, 6 dispatches:
//  1. zero:   cnt[n_vox], spill_n, ovf_n, lo, hi = 0
//  2. build:  r = atomicAdd(&cnt[v],1); r<K ? bucket[v*K+r]=pid : spill (+ovf)
//  3. vfill:  cnt[v]<=5 ? vlist[lo++]=v : vlist[n_vox-1 - hi++]=v
//             (two cursors, one array: provably complete & disjoint)
//  4. fused:  16 thr/voxel in vlist order (waves get count-similar voxels):
//             3-deep pipelined gather, gate MLP (DPP shfl), softmax,
//             nt-store fuse, reg accumulate; v_new=acc/max(n,1) if n<=K
//  5. spill:  rare points past K: fuse row + float-atomicAdd into v_new
//  6. ovfdiv: divide overflow voxels' v_new by cnt (ovf list)
// K=14 so total ws footprint (cnt+hdr + 14*nv + np + nv + nv) is STRICTLY
// smaller than R8's proven 16*nv layout.
// ---------------------------------------------------------------------------

__global__ __launch_bounds__(256) void zero_kernel(int* __restrict__ p, int n)
{
    int i = blockIdx.x * blockDim.x + threadIdx.x;
    if (i < n) p[i] = 0;
}

__global__ __launch_bounds__(256) void build_kernel(
    const int* __restrict__ p2v, int* __restrict__ cnt,
    int* __restrict__ bucket, int* __restrict__ spill, int* __restrict__ spill_n,
    int* __restrict__ ovf, int* __restrict__ ovf_n, int n_pts, int K)
{
    int i = blockIdx.x * blockDim.x + threadIdx.x;
    if (i >= n_pts) return;
    const int v = p2v[i];
    const int r = atomicAdd(&cnt[v], 1);
    if (r < K) {
        bucket[(size_t)v * K + r] = i;
    } else {
        if (r == K) {                 // exactly one trigger per ovf voxel
            int o = atomicAdd(ovf_n, 1);
            ovf[o] = v;
        }
        int s = atomicAdd(spill_n, 1);
        spill[s] = i;
    }
}

__global__ __launch_bounds__(256) void vfill_kernel(
    const int* __restrict__ cnt, int* __restrict__ vlist,
    int* __restrict__ lo, int* __restrict__ hi, int n_vox, int thr)
{
    int i = blockIdx.x * blockDim.x + threadIdx.x;
    if (i >= n_vox) return;
    if (cnt[i] <= thr) {
        vlist[atomicAdd(lo, 1)] = i;                 // grows up from 0
    } else {
        vlist[n_vox - 1 - atomicAdd(hi, 1)] = i;     // grows down from end
    }
}

__global__ __launch_bounds__(256) void fused_kernel(
    const float* __restrict__ p_feats, const float* __restrict__ v_feats,
    const float* __restrict__ Wp, const float* __restrict__ bp,
    const float* __restrict__ Wv, const float* __restrict__ bv,
    const int* __restrict__ cnt, const int* __restrict__ bucket,
    const int* __restrict__ vlist,
    float* __restrict__ fuse_out, float* __restrict__ v_new, int n_vox, int K)
{
    const int gid = blockIdx.x * blockDim.x + threadIdx.x;
    const int g = gid >> 4;          // 16 threads per voxel-slot
    const int t = gid & 15;          // 4 channels per thread
    if (g >= n_vox) return;
    const int v = vlist[g];          // bimodal order: wave-similar counts
    if ((unsigned)v >= (unsigned)n_vox) return;   // uniform per group

    const f4* Wp4 = (const f4*)Wp;
    const f4* Wv4 = (const f4*)Wv;
    const f4 wpA = Wp4[2 * t], wpB = Wp4[2 * t + 1];
    const f4 wvA = Wv4[2 * t], wvB = Wv4[2 * t + 1];
    const float bias0 = bp[0] + bv[0];
    const float bias1 = bp[1] + bv[1];

    const f4 vf = *(const f4*)(v_feats + (size_t)v * C + t * 4);

    float lv0 = vf.x * wvA.x + vf.y * wvA.z + vf.z * wvB.x + vf.w * wvB.z;
    float lv1 = vf.x * wvA.y + vf.y * wvA.w + vf.z * wvB.y + vf.w * wvB.w;
    #pragma unroll
    for (int m = 1; m < 16; m <<= 1) {
        lv0 += __shfl_xor(lv0, m);
        lv1 += __shfl_xor(lv1, m);
    }
    lv0 += bias0;
    lv1 += bias1;

    const int n = cnt[v];
    const int m = min(n, K);
    const size_t b0 = (size_t)v * K;
    f4 acc = (f4){0.f, 0.f, 0.f, 0.f};

    // 3-deep software pipeline (nt on zero-reuse streams)
    int pidA = 0, pidB = 0, pidC = 0;
    f4 pfA = (f4){0.f, 0.f, 0.f, 0.f}, pfB = pfA, pfC = pfA;
    if (m > 0) {
        pidA = bucket[b0];
        pfA = __builtin_nontemporal_load((const f4*)(p_feats + (size_t)pidA * C + t * 4));
    }
    if (m > 1) {
        pidB = bucket[b0 + 1];
        pfB = __builtin_nontemporal_load((const f4*)(p_feats + (size_t)pidB * C + t * 4));
    }
    if (m > 2) {
        pidC = bucket[b0 + 2];
        pfC = __builtin_nontemporal_load((const f4*)(p_feats + (size_t)pidC * C + t * 4));
    }

    for (int i = 0; i < m; i++) {
        const int pid = pidA;
        const f4 pf = pfA;
        pidA = pidB; pfA = pfB;
        pidB = pidC; pfB = pfC;
        if (i + 3 < m) {
            pidC = bucket[b0 + i + 3];
            pfC = __builtin_nontemporal_load((const f4*)(p_feats + (size_t)pidC * C + t * 4));
        }

        float l0 = pf.x * wpA.x + pf.y * wpA.z + pf.z * wpB.x + pf.w * wpB.z;
        float l1 = pf.x * wpA.y + pf.y * wpA.w + pf.z * wpB.y + pf.w * wpB.w;
        #pragma unroll
        for (int mm = 1; mm < 16; mm <<= 1) {
            l0 += __shfl_xor(l0, mm);
            l1 += __shfl_xor(l1, mm);
        }
        l0 += lv0;
        l1 += lv1;

        const float mx = fmaxf(l0, l1);
        const float e0 = __expf(l0 - mx), e1 = __expf(l1 - mx);
        const float w0 = e0 / (e0 + e1);
        const float w1 = 1.0f - w0;

        f4 f;
        f.x = pf.x * w0 + vf.x * w1;
        f.y = pf.y * w0 + vf.y * w1;
        f.z = pf.z * w0 + vf.z * w1;
        f.w = pf.w * w0 + vf.w * w1;

        __builtin_nontemporal_store(f, (f4*)(fuse_out + (size_t)pid * C + t * 4));
        acc.x += f.x; acc.y += f.y; acc.z += f.z; acc.w += f.w;
    }

    if (n <= K) {
        const float inv = 1.0f / (float)max(n, 1);
        f4 r;
        r.x = acc.x * inv; r.y = acc.y * inv; r.z = acc.z * inv; r.w = acc.w * inv;
        *(f4*)(v_new + (size_t)v * C + t * 4) = r;
    } else {
        // overflow voxel: raw partial sum; spill adds rest; ovfdiv divides
        *(f4*)(v_new + (size_t)v * C + t * 4) = acc;
    }
}

__global__ __launch_bounds__(256) void spill_kernel(
    const float* __restrict__ p_feats, const float* __restrict__ v_feats,
    const float* __restrict__ Wp, const float* __restrict__ bp,
    const float* __restrict__ Wv, const float* __restrict__ bv,
    const int* __restrict__ p2v, const int* __restrict__ spill,
    const int* __restrict__ spill_n,
    float* __restrict__ fuse_out, float* __restrict__ v_new)
{
    const int sn = *spill_n;
    const int total = sn * 16;
    const int T_all = gridDim.x * blockDim.x;
    const int gtid = blockIdx.x * blockDim.x + threadIdx.x;

    for (int slot = gtid; slot < total; slot += T_all) {
        const int j = slot >> 4;
        const int t = slot & 15;

        const int pid = spill[j];
        const int v = p2v[pid];

        const f4* Wp4 = (const f4*)Wp;
        const f4* Wv4 = (const f4*)Wv;
        const f4 wpA = Wp4[2 * t], wpB = Wp4[2 * t + 1];
        const f4 wvA = Wv4[2 * t], wvB = Wv4[2 * t + 1];

        const f4 vf = *(const f4*)(v_feats + (size_t)v * C + t * 4);
        const f4 pf = *(const f4*)(p_feats + (size_t)pid * C + t * 4);

        float l0 = pf.x * wpA.x + pf.y * wpA.z + pf.z * wpB.x + pf.w * wpB.z
                 + vf.x * wvA.x + vf.y * wvA.z + vf.z * wvB.x + vf.w * wvB.z;
        float l1 = pf.x * wpA.y + pf.y * wpA.w + pf.z * wpB.y + pf.w * wpB.w
                 + vf.x * wvA.y + vf.y * wvA.w + vf.z * wvB.y + vf.w * wvB.w;
        #pragma unroll
        for (int m = 1; m < 16; m <<= 1) {
            l0 += __shfl_xor(l0, m);
            l1 += __shfl_xor(l1, m);
        }
        l0 += bp[0] + bv[0];
        l1 += bp[1] + bv[1];

        const float mx = fmaxf(l0, l1);
        const float e0 = __expf(l0 - mx), e1 = __expf(l1 - mx);
        const float w0 = e0 / (e0 + e1);
        const float w1 = 1.0f - w0;

        f4 f;
        f.x = pf.x * w0 + vf.x * w1;
        f.y = pf.y * w0 + vf.y * w1;
        f.z = pf.z * w0 + vf.z * w1;
        f.w = pf.w * w0 + vf.w * w1;

        *(f4*)(fuse_out + (size_t)pid * C + t * 4) = f;

        float* s = v_new + (size_t)v * C + t * 4;
        atomicAdd(s + 0, f.x);
        atomicAdd(s + 1, f.y);
        atomicAdd(s + 2, f.z);
        atomicAdd(s + 3, f.w);
    }
}

__global__ __launch_bounds__(256) void ovfdiv_kernel(
    const int* __restrict__ ovf, const int* __restrict__ ovf_n,
    const int* __restrict__ cnt, float* __restrict__ v_new)
{
    const int on = *ovf_n;
    const int total = on * 16;
    const int T_all = gridDim.x * blockDim.x;
    const int gtid = blockIdx.x * blockDim.x + threadIdx.x;

    for (int slot = gtid; slot < total; slot += T_all) {
        const int j = slot >> 4;
        const int t = slot & 15;
        const int v = ovf[j];
        const float inv = 1.0f / (float)cnt[v];
        f4* p = (f4*)(v_new + (size_t)v * C + t * 4);
        f4 x = *p;
        x.x *= inv; x.y *= inv; x.z *= inv; x.w *= inv;
        *p = x;
    }
}

extern "C" void kernel_launch(void* const* d_in, const int* in_sizes, int n_in,
                              void* d_out, int out_size, void* d_ws, size_t ws_size,
                              hipStream_t stream) {
    const float* p_feats = (const float*)d_in[0];
    const float* v_feats = (const float*)d_in[1];
    const float* Wp = (const float*)d_in[2];
    const float* bp = (const float*)d_in[3];
    const float* Wv = (const float*)d_in[4];
    const float* bv = (const float*)d_in[5];
    const int* p2v = (const int*)d_in[6];

    const int n_pts = in_sizes[0] / C;
    const int n_vox = in_sizes[1] / C;

    float* fuse_out = (float*)d_out;
    float* v_new = fuse_out + (size_t)n_pts * C;

    // ws layout (ints): cnt[n_vox] | spill_n | ovf_n | lo | hi | pad->16
    //                 | bucket[n_vox*K] | spill[n_pts] | ovf[n_vox] | vlist[n_vox]
    // K=14 keeps total strictly below R8's proven K=16 footprint.
    const size_t ws_ints = ws_size / sizeof(int);
    const size_t fixed = (size_t)n_vox + 16 + (size_t)n_pts + 2 * (size_t)n_vox;
    long long avail = (long long)ws_ints - (long long)fixed;
    int K = 14;
    if (avail < (long long)n_vox * K) K = (int)(avail / (long long)n_vox);
    if (K < 1) K = 1;

    int* cnt = (int*)d_ws;
    int* spill_n = cnt + n_vox;
    int* ovf_n = spill_n + 1;
    int* lo = ovf_n + 1;
    int* hi = lo + 1;
    int* bucket = cnt + n_vox + 16;
    int* spill = bucket + (size_t)n_vox * K;
    int* ovf = spill + n_pts;
    int* vlist = ovf + n_vox;

    const int T = 256;
    const int thr = 5;   // bimodal split threshold (ordering heuristic only)

    zero_kernel<<<(n_vox + 4 + T - 1) / T, T, 0, stream>>>(cnt, n_vox + 4);
    build_kernel<<<(n_pts + T - 1) / T, T, 0, stream>>>(
        p2v, cnt, bucket, spill, spill_n, ovf, ovf_n, n_pts, K);
    vfill_kernel<<<(n_vox + T - 1) / T, T, 0, stream>>>(
        cnt, vlist, lo, hi, n_vox, thr);
    fused_kernel<<<((size_t)n_vox * 16 + T - 1) / T, T, 0, stream>>>(
        p_feats, v_feats, Wp, bp, Wv, bv, cnt, bucket, vlist,
        fuse_out, v_new, n_vox, K);
    spill_kernel<<<32, T, 0, stream>>>(
        p_feats, v_feats, Wp, bp, Wv, bv, p2v, spill, spill_n,
        fuse_out, v_new);
    ovfdiv_kernel<<<16, T, 0, stream>>>(ovf, ovf_n, cnt, v_new);
}

// Round 12
// 406.006 us; speedup vs baseline: 1.4182x; 1.4182x over previous
//
#include <hip/hip_runtime.h>

#define C 64

typedef float f4 __attribute__((ext_vector_type(4)));

// ---------------------------------------------------------------------------
// R8 structure (proven 434us), fused loop upgraded to chunked 6-wide prefetch:
//  1. zero:   cnt[n_vox], spill_n, ovf_n = 0
//  2. build:  r = atomicAdd(&cnt[v],1); r<K ? bucket[v*K+r]=pid : spill (+ovf)
//  3. fused:  16 thr/voxel IN VOXEL ORDER (sequential v-side streams).
//             Lane-parallel bucket load + shfl broadcast; chunks of 6 rows
//             issued back-to-back (all of an avg voxel's points in flight).
//  4. spill:  rare points past K: fuse row + float-atomicAdd into v_new
//  5. ovfdiv: divide overflow voxels' v_new by cnt
// ---------------------------------------------------------------------------

__global__ __launch_bounds__(256) void zero_kernel(int* __restrict__ p, int n)
{
    int i = blockIdx.x * blockDim.x + threadIdx.x;
    if (i < n) p[i] = 0;
}

__global__ __launch_bounds__(256) void build_kernel(
    const int* __restrict__ p2v, int* __restrict__ cnt,
    int* __restrict__ bucket, int* __restrict__ spill, int* __restrict__ spill_n,
    int* __restrict__ ovf, int* __restrict__ ovf_n, int n_pts, int K)
{
    int i = blockIdx.x * blockDim.x + threadIdx.x;
    if (i >= n_pts) return;
    const int v = p2v[i];
    const int r = atomicAdd(&cnt[v], 1);
    if (r < K) {
        bucket[(size_t)v * K + r] = i;
    } else {
        if (r == K) {                 // exactly one trigger per ovf voxel
            int o = atomicAdd(ovf_n, 1);
            ovf[o] = v;
        }
        int s = atomicAdd(spill_n, 1);
        spill[s] = i;
    }
}

__global__ __launch_bounds__(256) void fused_kernel(
    const float* __restrict__ p_feats, const float* __restrict__ v_feats,
    const float* __restrict__ Wp, const float* __restrict__ bp,
    const float* __restrict__ Wv, const float* __restrict__ bv,
    const int* __restrict__ cnt, const int* __restrict__ bucket,
    float* __restrict__ fuse_out, float* __restrict__ v_new, int n_vox, int K)
{
    const int gid = blockIdx.x * blockDim.x + threadIdx.x;
    const int v = gid >> 4;          // 16 threads per voxel, voxel order = id
    const int t = gid & 15;          // 4 channels per thread
    if (v >= n_vox) return;

    const f4* Wp4 = (const f4*)Wp;
    const f4* Wv4 = (const f4*)Wv;
    const f4 wpA = Wp4[2 * t], wpB = Wp4[2 * t + 1];
    const f4 wvA = Wv4[2 * t], wvB = Wv4[2 * t + 1];
    const float bias0 = bp[0] + bv[0];
    const float bias1 = bp[1] + bv[1];

    const f4 vf = *(const f4*)(v_feats + (size_t)v * C + t * 4);

    // v-side logit contribution (computed once per voxel)
    float lv0 = vf.x * wvA.x + vf.y * wvA.z + vf.z * wvB.x + vf.w * wvB.z;
    float lv1 = vf.x * wvA.y + vf.y * wvA.w + vf.z * wvB.y + vf.w * wvB.w;
    #pragma unroll
    for (int m = 1; m < 16; m <<= 1) {
        lv0 += __shfl_xor(lv0, m);
        lv1 += __shfl_xor(lv1, m);
    }
    lv0 += bias0;
    lv1 += bias1;

    const int n = cnt[v];
    const int m = min(n, K);
    const size_t b0 = (size_t)v * K;
    f4 acc = (f4){0.f, 0.f, 0.f, 0.f};

    // lane-parallel bucket load: slot t's pid (one coalesced load per group)
    int pid_t = 0;
    if (t < m) pid_t = bucket[b0 + t];

    // chunks of 6: issue all rows of the chunk before any compute.
    // (avg count 5 => whole voxel in flight for ~75% of voxels)
#define LD(j, q, a)                                                             \
    if ((j) < rem) {                                                            \
        q = __shfl(pid_t, base + (j), 16);                                      \
        a = __builtin_nontemporal_load(                                         \
            (const f4*)(p_feats + (size_t)q * C + t * 4));                      \
    }

#define PROC(j, q, a)                                                           \
    if ((j) < rem) {                                                            \
        float l0 = a.x * wpA.x + a.y * wpA.z + a.z * wpB.x + a.w * wpB.z;       \
        float l1 = a.x * wpA.y + a.y * wpA.w + a.z * wpB.y + a.w * wpB.w;       \
        _Pragma("unroll")                                                       \
        for (int mm = 1; mm < 16; mm <<= 1) {                                   \
            l0 += __shfl_xor(l0, mm);                                           \
            l1 += __shfl_xor(l1, mm);                                           \
        }                                                                       \
        l0 += lv0;                                                              \
        l1 += lv1;                                                              \
        const float mx = fmaxf(l0, l1);                                         \
        const float e0 = __expf(l0 - mx), e1 = __expf(l1 - mx);                 \
        const float w0 = e0 / (e0 + e1);                                        \
        const float w1 = 1.0f - w0;                                             \
        f4 f;                                                                   \
        f.x = a.x * w0 + vf.x * w1;                                             \
        f.y = a.y * w0 + vf.y * w1;                                             \
        f.z = a.z * w0 + vf.z * w1;                                             \
        f.w = a.w * w0 + vf.w * w1;                                             \
        __builtin_nontemporal_store(f, (f4*)(fuse_out + (size_t)q * C + t * 4));\
        acc.x += f.x; acc.y += f.y; acc.z += f.z; acc.w += f.w;                 \
    }

    int base = 0;
    while (base < m) {
        const int rem = m - base;
        int q0 = 0, q1 = 0, q2 = 0, q3 = 0, q4 = 0, q5 = 0;
        f4 a0, a1, a2, a3, a4, a5;
        LD(0, q0, a0) LD(1, q1, a1) LD(2, q2, a2)
        LD(3, q3, a3) LD(4, q4, a4) LD(5, q5, a5)
        PROC(0, q0, a0) PROC(1, q1, a1) PROC(2, q2, a2)
        PROC(3, q3, a3) PROC(4, q4, a4) PROC(5, q5, a5)
        base += 6;
    }
#undef LD
#undef PROC

    if (n <= K) {
        const float inv = 1.0f / (float)max(n, 1);
        f4 r;
        r.x = acc.x * inv; r.y = acc.y * inv; r.z = acc.z * inv; r.w = acc.w * inv;
        *(f4*)(v_new + (size_t)v * C + t * 4) = r;
    } else {
        // overflow voxel: raw partial sum; spill adds rest; ovfdiv divides
        *(f4*)(v_new + (size_t)v * C + t * 4) = acc;
    }
}

__global__ __launch_bounds__(256) void spill_kernel(
    const float* __restrict__ p_feats, const float* __restrict__ v_feats,
    const float* __restrict__ Wp, const float* __restrict__ bp,
    const float* __restrict__ Wv, const float* __restrict__ bv,
    const int* __restrict__ p2v, const int* __restrict__ spill,
    const int* __restrict__ spill_n,
    float* __restrict__ fuse_out, float* __restrict__ v_new)
{
    const int sn = *spill_n;
    const int total = sn * 16;
    const int T_all = gridDim.x * blockDim.x;
    const int gtid = blockIdx.x * blockDim.x + threadIdx.x;

    for (int slot = gtid; slot < total; slot += T_all) {
        const int j = slot >> 4;
        const int t = slot & 15;

        const int pid = spill[j];
        const int v = p2v[pid];

        const f4* Wp4 = (const f4*)Wp;
        const f4* Wv4 = (const f4*)Wv;
        const f4 wpA = Wp4[2 * t], wpB = Wp4[2 * t + 1];
        const f4 wvA = Wv4[2 * t], wvB = Wv4[2 * t + 1];

        const f4 vf = *(const f4*)(v_feats + (size_t)v * C + t * 4);
        const f4 pf = *(const f4*)(p_feats + (size_t)pid * C + t * 4);

        float l0 = pf.x * wpA.x + pf.y * wpA.z + pf.z * wpB.x + pf.w * wpB.z
                 + vf.x * wvA.x + vf.y * wvA.z + vf.z * wvB.x + vf.w * wvB.z;
        float l1 = pf.x * wpA.y + pf.y * wpA.w + pf.z * wpB.y + pf.w * wpB.w
                 + vf.x * wvA.y + vf.y * wvA.w + vf.z * wvB.y + vf.w * wvB.w;
        #pragma unroll
        for (int m = 1; m < 16; m <<= 1) {
            l0 += __shfl_xor(l0, m);
            l1 += __shfl_xor(l1, m);
        }
        l0 += bp[0] + bv[0];
        l1 += bp[1] + bv[1];

        const float mx = fmaxf(l0, l1);
        const float e0 = __expf(l0 - mx), e1 = __expf(l1 - mx);
        const float w0 = e0 / (e0 + e1);
        const float w1 = 1.0f - w0;

        f4 f;
        f.x = pf.x * w0 + vf.x * w1;
        f.y = pf.y * w0 + vf.y * w1;
        f.z = pf.z * w0 + vf.z * w1;
        f.w = pf.w * w0 + vf.w * w1;

        *(f4*)(fuse_out + (size_t)pid * C + t * 4) = f;

        float* s = v_new + (size_t)v * C + t * 4;
        atomicAdd(s + 0, f.x);
        atomicAdd(s + 1, f.y);
        atomicAdd(s + 2, f.z);
        atomicAdd(s + 3, f.w);
    }
}

__global__ __launch_bounds__(256) void ovfdiv_kernel(
    const int* __restrict__ ovf, const int* __restrict__ ovf_n,
    const int* __restrict__ cnt, float* __restrict__ v_new)
{
    const int on = *ovf_n;
    const int total = on * 16;
    const int T_all = gridDim.x * blockDim.x;
    const int gtid = blockIdx.x * blockDim.x + threadIdx.x;

    for (int slot = gtid; slot < total; slot += T_all) {
        const int j = slot >> 4;
        const int t = slot & 15;
        const int v = ovf[j];
        const float inv = 1.0f / (float)cnt[v];
        f4* p = (f4*)(v_new + (size_t)v * C + t * 4);
        f4 x = *p;
        x.x *= inv; x.y *= inv; x.z *= inv; x.w *= inv;
        *p = x;
    }
}

extern "C" void kernel_launch(void* const* d_in, const int* in_sizes, int n_in,
                              void* d_out, int out_size, void* d_ws, size_t ws_size,
                              hipStream_t stream) {
    const float* p_feats = (const float*)d_in[0];
    const float* v_feats = (const float*)d_in[1];
    const float* Wp = (const float*)d_in[2];
    const float* bp = (const float*)d_in[3];
    const float* Wv = (const float*)d_in[4];
    const float* bv = (const float*)d_in[5];
    const int* p2v = (const int*)d_in[6];

    const int n_pts = in_sizes[0] / C;
    const int n_vox = in_sizes[1] / C;

    float* fuse_out = (float*)d_out;
    float* v_new = fuse_out + (size_t)n_pts * C;

    // ws layout (ints): cnt[n_vox] | spill_n | ovf_n | pad->16
    //                 | bucket[n_vox*K] | spill[n_pts] | ovf[n_vox]
    // identical to the R8 run that passed.
    const size_t ws_ints = ws_size / sizeof(int);
    const size_t fixed = (size_t)n_vox + 16 + (size_t)n_pts + (size_t)n_vox;
    long long avail = (long long)ws_ints - (long long)fixed;
    int K = 16;
    if (avail < (long long)n_vox * K) K = (int)(avail / (long long)n_vox);
    if (K < 1) K = 1;

    int* cnt = (int*)d_ws;
    int* spill_n = cnt + n_vox;
    int* ovf_n = spill_n + 1;
    int* bucket = cnt + n_vox + 16;
    int* spill = bucket + (size_t)n_vox * K;
    int* ovf = spill + n_pts;

    const int T = 256;

    zero_kernel<<<(n_vox + 2 + T - 1) / T, T, 0, stream>>>(cnt, n_vox + 2);
    build_kernel<<<(n_pts + T - 1) / T, T, 0, stream>>>(
        p2v, cnt, bucket, spill, spill_n, ovf, ovf_n, n_pts, K);
    fused_kernel<<<((size_t)n_vox * 16 + T - 1) / T, T, 0, stream>>>(
        p_feats, v_feats, Wp, bp, Wv, bv, cnt, bucket,
        fuse_out, v_new, n_vox, K);
    spill_kernel<<<32, T, 0, stream>>>(
        p_feats, v_feats, Wp, bp, Wv, bv, p2v, spill, spill_n,
        fuse_out, v_new);
    ovfdiv_kernel<<<16, T, 0, stream>>>(ovf, ovf_n, cnt, v_new);
}